// Round 3
// baseline (129.798 us; speedup 1.0000x reference)
//
#include <hip/hip_runtime.h>
#include <hip/hip_bf16.h>

// MoEStage: B=32 T=2048 DM=128 DFE=64 DH=64 DRH=64 E=8 NF=16 NSF=64 TOPK=2
// K0 : fold weights (Wf@We1f, Wp@Wr1[128:]) + pre-swizzled bf16 B-tiles in ws
// K1 : LN (4 lanes/token) + tiled f32 router GEMM + top2 + lists + gates
// K1b: per-expert segment prefix (1 block)
// K2 : per-expert gathered MFMA bf16 dual-GEMM + gelu -> eoTok[t][which] bf16
// K3 : out = hidden + alpha*(g1*eo1 + g2*eo2)   (pure BW gather)

typedef unsigned short u16;
typedef __attribute__((ext_vector_type(8))) short bfrag;    // 8 bf16 (MFMA A/B)
typedef __attribute__((ext_vector_type(8))) u16 u16x8;
typedef __attribute__((ext_vector_type(4))) float facc;     // MFMA C/D
typedef __attribute__((ext_vector_type(4))) float f32x4;

#define NTOK 65536
#define CAP 65536

// ws layout (bytes)
#define OFF_CNT   ((size_t)0)                               // 8*4 (zeroed per call)
#define OFF_SEGM  ((size_t)256)                             // 16*4 seg prefix
#define OFF_LTOK  ((size_t)512)                             // 8*CAP*4, entries (t<<1)|which
#define OFF_SMAPG (OFF_LTOK + (size_t)8*CAP*4)              // NTOK * float2 gates
#define OFF_HWS   (OFF_SMAPG + (size_t)NTOK*8)              // NTOK*128 bf16
#define OFF_EOTOK (OFF_HWS + (size_t)NTOK*128*2)            // NTOK*2*128 bf16
#define OFF_W1T   (OFF_EOTOK + (size_t)NTOK*2*128*2)        // 8*64*192*2 swizzled
#define OFF_W2T   (OFF_W1T + 196608)                        // 8*128*64*2 swizzled
#define OFF_B1P   (OFF_W2T + 131072)                        // 8*64*4
#define OFF_WPR   (OFF_B1P + 2048)                          // 64*64*4
#define OFF_BR1P  (OFF_WPR + 16384)                         // 64*4

__device__ __forceinline__ u16 f2bf(float f) {
  union { __hip_bfloat16 h; u16 u; } cv;
  cv.h = __float2bfloat16(f);
  return cv.u;
}
__device__ __forceinline__ float bf2f(u16 u) {
  return __uint_as_float(((unsigned)u) << 16);
}

// ---------------- K0: weight folding + pre-swizzled bf16 tiles ----------------
__global__ __launch_bounds__(256)
void k0_pre(const float* __restrict__ Wp, const float* __restrict__ bp,
            const float* __restrict__ Wr1, const float* __restrict__ br1,
            const float* __restrict__ Wf, const float* __restrict__ bfv,
            const float* __restrict__ We1h, const float* __restrict__ We1f,
            const float* __restrict__ be1, const float* __restrict__ We2,
            float* __restrict__ Wpr, float* __restrict__ br1p,
            u16* __restrict__ w1t, u16* __restrict__ w2t, float* __restrict__ b1p)
{
  int j = blockIdx.x * 256 + threadIdx.x;
  if (j < 4096) {                       // Wpr[i][o] = sum_k Wp[i][k] * Wr1[128+k][o]
    int i = j >> 6, o = j & 63;
    float s = 0.f;
    for (int k = 0; k < 64; ++k) s += Wp[i*64+k] * Wr1[(128+k)*64 + o];
    Wpr[i*64+o] = s;
  } else if (j < 4160) {                // br1p[o] = br1[o] + sum_k bp[k]*Wr1[128+k][o]
    int o = j - 4096;
    float s = br1[o];
    for (int k = 0; k < 64; ++k) s += bp[k] * Wr1[(128+k)*64 + o];
    br1p[o] = s;
  } else if (j < 4160 + 98304) {        // w1t[e][jj][k] (B^T tile, swizzled)
    int idx = j - 4160;
    int e = idx / 12288; int rem = idx % 12288;
    int jj = rem / 192; int k = rem % 192;
    float v = 0.f;
    if (k < 128) v = We1h[(e*128 + k)*64 + jj];
    else if (k < 144) {                 // (Wf @ We1f)[k-128][jj]
      int i = k - 128; float s = 0.f;
      for (int d = 0; d < 64; ++d) s += Wf[(e*16+i)*64 + d] * We1f[(e*64+d)*64 + jj];
      v = s;
    }                                   // k in [144,192): zero pad
    size_t byte = (size_t)(e*64 + jj)*384 + ((2*k) ^ ((jj & 7) << 4));
    *(u16*)((char*)w1t + byte) = f2bf(v);
  } else if (j < 4160 + 98304 + 65536) { // w2t[e][d][k] = We2[e][k][d] (swizzled)
    int idx = j - 4160 - 98304;
    int e = idx / 8192; int rem = idx % 8192;
    int d = rem / 64; int k = rem & 63;
    float v = We2[(e*64 + k)*128 + d];
    size_t byte = (size_t)(e*128 + d)*128 + ((2*k) ^ ((d & 7) << 4));
    *(u16*)((char*)w2t + byte) = f2bf(v);
  } else if (j < 4160 + 98304 + 65536 + 512) { // b1p[e][o] = be1 + bf@We1f
    int idx = j - 4160 - 98304 - 65536;
    int e = idx >> 6, o = idx & 63;
    float s = be1[e*64 + o];
    for (int d = 0; d < 64; ++d) s += bfv[e*64 + d] * We1f[(e*64+d)*64 + o];
    b1p[e*64 + o] = s;
  }
}

// ---------------- K1: LN + tiled f32 router GEMM + top2 + lists ----------------
// 256 threads = 4 waves, 64 tokens/block, grid 1024. LN: 4 lanes/token.
// GEMM: Z[64][64] = rin[64][192] @ W[192][64] in 3 K-chunks of 64.
__global__ __launch_bounds__(256, 4)
void k1_router(const float* __restrict__ hidden, const float* __restrict__ feat,
               const float* __restrict__ ln_g, const float* __restrict__ ln_b,
               const float* __restrict__ Wr1, const float* __restrict__ Wr2,
               const float* __restrict__ br2, const int* __restrict__ seqlen,
               const int* __restrict__ sidx_g,
               const float* __restrict__ Wpr, const float* __restrict__ br1p,
               float* __restrict__ outG, float* __restrict__ outP,
               u16* __restrict__ hws, int* __restrict__ cnt,
               int* __restrict__ listTok, float* __restrict__ smapG)
{
  __shared__ float At[64*64];      // [k][tok] f32, swizzled at 4-token granularity
  __shared__ float Wc[64*64];      // [k][out]
  __shared__ float sW2[512];       // Wr2 [out][e]
  __shared__ float sb1[64], sg[128], sb[128], sbr2[8];
  __shared__ int ssidx[64];
  __shared__ int lcnt[8], lbase[8];
  __shared__ int ltok[8][64];      // entries (t<<1)|which
  __shared__ float tg[64][2];      // per local token (g1,g2), 0 if invalid

  int tid = threadIdx.x;
  for (int i = tid; i < 512; i += 256) sW2[i] = Wr2[i];
  if (tid < 128) sg[tid] = ln_g[tid]; else sb[tid-128] = ln_b[tid-128];
  if (tid < 64) { sb1[tid] = br1p[tid]; ssidx[tid] = sidx_g[tid]; }
  if (tid >= 64 && tid < 72) sbr2[tid-64] = br2[tid-64];
  if (tid >= 72 && tid < 80) lcnt[tid-72] = 0;
  __syncthreads();

  int tok = tid >> 2, q = tid & 3;           // 4 lanes per token
  int t = blockIdx.x * 64 + tok;

  // ---- Phase A: LN (cols q*32 .. q*32+31 per lane) ----
  f32x4 x[8];
  #pragma unroll
  for (int i = 0; i < 8; ++i) x[i] = *(const f32x4*)(hidden + (size_t)t*128 + q*32 + i*4);
  float s = 0.f;
  #pragma unroll
  for (int i = 0; i < 8; ++i) { s += x[i][0] + x[i][1]; s += x[i][2] + x[i][3]; }
  s += __shfl_xor(s, 1, 64); s += __shfl_xor(s, 2, 64);
  float mu = s * (1.f/128.f);
  float v = 0.f;
  #pragma unroll
  for (int i = 0; i < 8; ++i) {
    #pragma unroll
    for (int j = 0; j < 4; ++j) { float d = x[i][j] - mu; v = fmaf(d, d, v); }
  }
  v += __shfl_xor(v, 1, 64); v += __shfl_xor(v, 2, 64);
  float rs = rsqrtf(v * (1.f/128.f) + 1e-5f);
  #pragma unroll
  for (int i = 0; i < 8; ++i) {
    #pragma unroll
    for (int j = 0; j < 4; ++j) {
      int c = q*32 + i*4 + j;
      x[i][j] = (x[i][j] - mu) * rs * sg[c] + sb[c];
    }
  }
  // hws write (bf16, 4 x u16x8)
  #pragma unroll
  for (int m = 0; m < 4; ++m) {
    u16x8 o;
    #pragma unroll
    for (int j = 0; j < 4; ++j) { o[j] = f2bf(x[2*m][j]); o[4+j] = f2bf(x[2*m+1][j]); }
    *(u16x8*)(hws + (size_t)t*128 + q*32 + m*8) = o;
  }
  // feat gather (16 per lane -> 64 per token)
  float fv[16];
  #pragma unroll
  for (int i = 0; i < 16; ++i) fv[i] = feat[(size_t)t*64 + ssidx[q*16 + i]];

  // ---- Phase B: 3 K-chunks of f32 GEMM ----
  float acc[4][4];
  #pragma unroll
  for (int i = 0; i < 4; ++i)
    #pragma unroll
    for (int p = 0; p < 4; ++p) acc[i][p] = 0.f;

  int tb = tid >> 4;                 // token-block (4 tokens) this lane reads
  int ob = (tid & 15) * 4;           // first output col this lane owns

  #pragma unroll 1
  for (int c = 0; c < 3; ++c) {
    __syncthreads();                 // previous chunk reads done
    // stage A^T chunk
    if (c < 2) {
      if ((c == 0) ? (q < 2) : (q >= 2)) {
        int kbase = (c == 0) ? q*32 : (q-2)*32;
        #pragma unroll
        for (int i = 0; i < 8; ++i)
          #pragma unroll
          for (int j = 0; j < 4; ++j) {
            int kr = kbase + i*4 + j;
            int byte = (kr << 8) + ((((tok >> 2) ^ ((kr >> 2) & 15)) << 4) | ((tok & 3) << 2));
            *(float*)((char*)At + byte) = x[i][j];
          }
      }
    } else {
      #pragma unroll
      for (int i = 0; i < 16; ++i) {
        int kr = q*16 + i;
        int byte = (kr << 8) + ((((tok >> 2) ^ ((kr >> 2) & 15)) << 4) | ((tok & 3) << 2));
        *(float*)((char*)At + byte) = fv[i];
      }
    }
    // stage W chunk
    const float* wsrc = (c == 0) ? Wr1 : (c == 1) ? (Wr1 + 4096) : Wpr;
    for (int i = tid; i < 1024; i += 256) ((f32x4*)Wc)[i] = ((const f32x4*)wsrc)[i];
    __syncthreads();
    #pragma unroll 4
    for (int k = 0; k < 64; ++k) {
      f32x4 a4 = *(const f32x4*)((const char*)At + (k << 8) + ((tb ^ ((k >> 2) & 15)) << 4));
      f32x4 b4 = *(const f32x4*)(Wc + k*64 + ob);
      #pragma unroll
      for (int i = 0; i < 4; ++i)
        #pragma unroll
        for (int p = 0; p < 4; ++p)
          acc[i][p] = fmaf(a4[i], b4[p], acc[i][p]);
    }
  }

  // ---- Phase C: logits, softmax, top2, lists ----
  float w2r[4][8];
  #pragma unroll
  for (int p = 0; p < 4; ++p)
    #pragma unroll
    for (int e = 0; e < 8; ++e) w2r[p][e] = sW2[(ob + p)*8 + e];
  float b1r[4];
  #pragma unroll
  for (int p = 0; p < 4; ++p) b1r[p] = sb1[ob + p];

  int j16 = tid & 15;
  #pragma unroll 1
  for (int ti = 0; ti < 4; ++ti) {
    float lo[8];
    #pragma unroll
    for (int e = 0; e < 8; ++e) lo[e] = 0.f;
    #pragma unroll
    for (int p = 0; p < 4; ++p) {
      float z = fmaxf(acc[ti][p] + b1r[p], 0.f);
      #pragma unroll
      for (int e = 0; e < 8; ++e) lo[e] = fmaf(z, w2r[p][e], lo[e]);
    }
    #pragma unroll
    for (int m = 1; m < 16; m <<= 1) {
      #pragma unroll
      for (int e = 0; e < 8; ++e) lo[e] += __shfl_xor(lo[e], m, 64);
    }
    #pragma unroll
    for (int e = 0; e < 8; ++e) lo[e] += sbr2[e];

    int tloc = tb*4 + ti;
    int tt = blockIdx.x*64 + tloc;
    float mx = lo[0];
    #pragma unroll
    for (int e = 1; e < 8; ++e) mx = fmaxf(mx, lo[e]);
    float ex[8]; float ss = 0.f;
    #pragma unroll
    for (int e = 0; e < 8; ++e) { ex[e] = __expf(lo[e] - mx); ss += ex[e]; }
    float inv = 1.f / ss;
    float p[8];
    #pragma unroll
    for (int e = 0; e < 8; ++e) p[e] = ex[e] * inv;
    float p1 = p[0]; int i1 = 0;
    #pragma unroll
    for (int e = 1; e < 8; ++e) { bool tk2 = p[e] > p1; p1 = tk2 ? p[e] : p1; i1 = tk2 ? e : i1; }
    float p2 = -1.f; int i2 = 0;
    #pragma unroll
    for (int e = 0; e < 8; ++e) { bool tk2 = (e != i1) && (p[e] > p2); p2 = tk2 ? p[e] : p2; i2 = tk2 ? e : i2; }
    bool valid = (tt & 2047) < seqlen[tt >> 11];
    float gden = 1.f / (p1 + p2);
    float g1 = p1 * gden, g2 = p2 * gden;
    float pv = p[0];
    #pragma unroll
    for (int e = 1; e < 8; ++e) pv = (j16 == e) ? p[e] : pv;
    if (j16 < 8) outP[(size_t)tt*8 + j16] = pv;
    float gv = (j16 == i1) ? g1 : ((j16 == i2) ? g2 : 0.f);
    if (!valid) gv = 0.f;
    if (j16 < 8) outG[(size_t)tt*8 + j16] = gv;
    if (j16 == 0) {
      if (valid) {
        int lp = atomicAdd(&lcnt[i1], 1); ltok[i1][lp] = (tt << 1);
        lp = atomicAdd(&lcnt[i2], 1);     ltok[i2][lp] = (tt << 1) | 1;
        tg[tloc][0] = g1; tg[tloc][1] = g2;
      } else {
        tg[tloc][0] = 0.f; tg[tloc][1] = 0.f;
      }
    }
  }

  __syncthreads();
  if (tid < 8) lbase[tid] = atomicAdd(&cnt[tid], lcnt[tid]);
  __syncthreads();
  #pragma unroll 1
  for (int e = 0; e < 8; ++e) {
    int ncnt = lcnt[e];
    if (tid < ncnt) listTok[(size_t)e*CAP + lbase[e] + tid] = ltok[e][tid];
  }
  if (tid < 64) {
    float2 g; g.x = tg[tid][0]; g.y = tg[tid][1];
    ((float2*)smapG)[blockIdx.x*64 + tid] = g;
  }
}

// ---------------- K1b: segment prefix ----------------
__global__ void k1b_prefix(const int* __restrict__ cnt, int* __restrict__ segm)
{
  if (threadIdx.x == 0 && blockIdx.x == 0) {
    int s = 0;
    #pragma unroll
    for (int e = 0; e < 8; ++e) { segm[e] = s; s += (cnt[e] + 63) >> 6; }
    segm[8] = s;
  }
}

// ---------------- K2: gathered expert MFMA dual-GEMM -> eoTok ----------------
__global__ __launch_bounds__(256)
void k2_experts(const float* __restrict__ feat, const u16* __restrict__ hws,
                const u16* __restrict__ w1t, const u16* __restrict__ w2t,
                const float* __restrict__ b1p, const float* __restrict__ be2,
                const int* __restrict__ eidx_g, const int* __restrict__ cnt,
                const int* __restrict__ segm, const int* __restrict__ listTok,
                u16* __restrict__ eoTok)
{
  __shared__ u16 Xs[64*192];    // X tile [row][k] swizzled, K padded to 160(+32)
  __shared__ u16 W1s[64*192];   // B^T [out j][k] swizzled
  __shared__ u16 W2s[128*64];   // B^T [out d][k] swizzled
  __shared__ u16 H1s[64*64];    // gelu output [row][j] swizzled
  __shared__ float b1s[64], be2s[128];
  __shared__ int sent[64];      // list entries (t<<1)|which
  __shared__ int seidx[16];
  __shared__ int snr;

  int b = blockIdx.x;
  if (b >= segm[8]) return;
  int e = 0;
  #pragma unroll
  for (int i = 1; i < 8; ++i) if (b >= segm[i]) e = i;
  int row0 = (b - segm[e]) << 6;
  int n = cnt[e];
  int nr = n - row0; if (nr > 64) nr = 64;
  int tid = threadIdx.x;
  if (tid == 0) snr = nr;

  if (tid < 64) {
    int ent = 0;
    if (tid < nr) ent = listTok[(size_t)e*CAP + row0 + tid];
    sent[tid] = ent;
    b1s[tid] = b1p[e*64 + tid];
  }
  if (tid >= 64 && tid < 192) be2s[tid - 64] = be2[e*128 + tid - 64];
  if (tid >= 192 && tid < 208) seidx[tid-192] = eidx_g[e*16 + tid - 192];
  {
    const u16x8* s1 = (const u16x8*)(w1t + e*64*192);
    u16x8* d1 = (u16x8*)W1s;
    for (int i = tid; i < 1536; i += 256) d1[i] = s1[i];
    const u16x8* s2 = (const u16x8*)(w2t + e*128*64);
    u16x8* d2 = (u16x8*)W2s;
    for (int i = tid; i < 1024; i += 256) d2[i] = s2[i];
  }
  __syncthreads();
  // X: h part (cols 0..127)
  for (int c = tid; c < 1024; c += 256) {
    int r = c >> 4, p = c & 15;
    u16x8 v = *(const u16x8*)(hws + (size_t)(sent[r] >> 1)*128 + p*8);
    *(u16x8*)((char*)Xs + r*384 + ((p*16) ^ ((r & 7) << 4))) = v;
  }
  // X: feat part (cols 128..143) + zero pad (144..159)
  if (tid < 128) {
    int r = tid >> 1, hf = tid & 1;
    int tk = sent[r] >> 1;
    u16x8 ov;
    #pragma unroll
    for (int p = 0; p < 8; ++p) ov[p] = f2bf(feat[(size_t)tk*64 + seidx[hf*8 + p]]);
    *(u16x8*)((char*)Xs + r*384 + ((256 + hf*16) ^ ((r & 7) << 4))) = ov;
    u16x8 zv = {0,0,0,0,0,0,0,0};
    *(u16x8*)((char*)Xs + r*384 + ((288 + hf*16) ^ ((r & 7) << 4))) = zv;
  }
  __syncthreads();

  int w = tid >> 6, lane = tid & 63;
  int la = lane & 15, lg = lane >> 4;
  int wm = (w >> 1) * 32, wn = (w & 1) * 32;

  facc acc[2][2];
  #pragma unroll
  for (int a = 0; a < 2; ++a)
    #pragma unroll
    for (int b2 = 0; b2 < 2; ++b2) { facc z = {0.f,0.f,0.f,0.f}; acc[a][b2] = z; }
  #pragma unroll
  for (int kc = 0; kc < 5; ++kc) {
    int kb = kc*64 + lg*16;
    bfrag af[2], bf2[2];
    #pragma unroll
    for (int mi = 0; mi < 2; ++mi) {
      int r = wm + mi*16 + la;
      af[mi] = *(const bfrag*)((const char*)Xs + r*384 + (kb ^ ((r & 7) << 4)));
    }
    #pragma unroll
    for (int ni = 0; ni < 2; ++ni) {
      int r = wn + ni*16 + la;
      bf2[ni] = *(const bfrag*)((const char*)W1s + r*384 + (kb ^ ((r & 7) << 4)));
    }
    #pragma unroll
    for (int mi = 0; mi < 2; ++mi)
      #pragma unroll
      for (int ni = 0; ni < 2; ++ni)
        acc[mi][ni] = __builtin_amdgcn_mfma_f32_16x16x32_bf16(af[mi], bf2[ni], acc[mi][ni], 0, 0, 0);
  }
  // bias + exact gelu -> H1s
  #pragma unroll
  for (int mi = 0; mi < 2; ++mi)
    #pragma unroll
    for (int ni = 0; ni < 2; ++ni)
      #pragma unroll
      for (int rg = 0; rg < 4; ++rg) {
        int r = wm + mi*16 + lg*4 + rg;
        int c = wn + ni*16 + la;
        float z = acc[mi][ni][rg] + b1s[c];
        float gl = 0.5f * z * (1.f + erff(z * 0.70710678118f));
        *(u16*)((char*)H1s + r*128 + ((2*c) ^ ((r & 7) << 4))) = f2bf(gl);
      }
  __syncthreads();

  facc acc2[2][4];
  #pragma unroll
  for (int a = 0; a < 2; ++a)
    #pragma unroll
    for (int b2 = 0; b2 < 4; ++b2) { facc z = {0.f,0.f,0.f,0.f}; acc2[a][b2] = z; }
  int wn2 = (w & 1) * 64;
  #pragma unroll
  for (int kc = 0; kc < 2; ++kc) {
    int kb = kc*64 + lg*16;
    bfrag af[2], bf2[4];
    #pragma unroll
    for (int mi = 0; mi < 2; ++mi) {
      int r = wm + mi*16 + la;
      af[mi] = *(const bfrag*)((const char*)H1s + r*128 + (kb ^ ((r & 7) << 4)));
    }
    #pragma unroll
    for (int ni = 0; ni < 4; ++ni) {
      int r = wn2 + ni*16 + la;
      bf2[ni] = *(const bfrag*)((const char*)W2s + r*128 + (kb ^ ((r & 7) << 4)));
    }
    #pragma unroll
    for (int mi = 0; mi < 2; ++mi)
      #pragma unroll
      for (int ni = 0; ni < 4; ++ni)
        acc2[mi][ni] = __builtin_amdgcn_mfma_f32_16x16x32_bf16(af[mi], bf2[ni], acc2[mi][ni], 0, 0, 0);
  }
  #pragma unroll
  for (int mi = 0; mi < 2; ++mi)
    #pragma unroll
    for (int ni = 0; ni < 4; ++ni)
      #pragma unroll
      for (int rg = 0; rg < 4; ++rg) {
        int r = wm + mi*16 + lg*4 + rg;
        int c = wn2 + ni*16 + la;
        if (r < snr) {
          float v = acc2[mi][ni][rg] + be2s[c];
          eoTok[(size_t)sent[r]*128 + c] = f2bf(v);
        }
      }
}

// ---------------- K3: combine out = hidden + a*(g1*eo1 + g2*eo2) ----------------
__global__ __launch_bounds__(256)
void k3_combine(const float* __restrict__ hidden, const float* __restrict__ smapG,
                const u16* __restrict__ eoTok, const float* __restrict__ alphap,
                float* __restrict__ outN)
{
  int tid = threadIdx.x;
  int tok = tid >> 2, q = tid & 3;
  int t = blockIdx.x*64 + tok;
  float2 g = ((const float2*)smapG)[t];
  float a = alphap[0];
  float ag0 = a * g.x, ag1 = a * g.y;
  const f32x4* hp = (const f32x4*)(hidden + (size_t)t*128 + q*32);
  f32x4* op = (f32x4*)(outN + (size_t)t*128 + q*32);
  const u16x8* e0 = (const u16x8*)(eoTok + ((size_t)t*2)*128 + q*32);
  const u16x8* e1 = (const u16x8*)(eoTok + ((size_t)t*2 + 1)*128 + q*32);
  #pragma unroll
  for (int i = 0; i < 4; ++i) {
    f32x4 r0 = hp[2*i], r1 = hp[2*i+1];
    if (g.x != 0.f) {
      u16x8 x0 = e0[i];
      #pragma unroll
      for (int j = 0; j < 4; ++j) { r0[j] = fmaf(ag0, bf2f(x0[j]), r0[j]); r1[j] = fmaf(ag0, bf2f(x0[4+j]), r1[j]); }
    }
    if (g.y != 0.f) {
      u16x8 x1 = e1[i];
      #pragma unroll
      for (int j = 0; j < 4; ++j) { r0[j] = fmaf(ag1, bf2f(x1[j]), r0[j]); r1[j] = fmaf(ag1, bf2f(x1[4+j]), r1[j]); }
    }
    op[2*i] = r0; op[2*i+1] = r1;
  }
}

// ---------------- launch ----------------
extern "C" void kernel_launch(void* const* d_in, const int* in_sizes, int n_in,
                              void* d_out, int out_size, void* d_ws, size_t ws_size,
                              hipStream_t stream) {
  const float* hidden = (const float*)d_in[0];
  const float* feat   = (const float*)d_in[1];
  const float* ln_g   = (const float*)d_in[2];
  const float* ln_b   = (const float*)d_in[3];
  const float* Wp     = (const float*)d_in[4];
  const float* bp     = (const float*)d_in[5];
  const float* Wr1    = (const float*)d_in[6];
  const float* br1    = (const float*)d_in[7];
  const float* Wr2    = (const float*)d_in[8];
  const float* br2    = (const float*)d_in[9];
  const float* Wf     = (const float*)d_in[10];
  const float* bfv    = (const float*)d_in[11];
  const float* We1h   = (const float*)d_in[12];
  const float* We1f   = (const float*)d_in[13];
  const float* be1    = (const float*)d_in[14];
  const float* We2    = (const float*)d_in[15];
  const float* be2    = (const float*)d_in[16];
  const float* alpha  = (const float*)d_in[17];
  const int* seqlen   = (const int*)d_in[18];
  const int* eidx     = (const int*)d_in[19];
  const int* sidx     = (const int*)d_in[20];

  char* ws = (char*)d_ws;
  int*   cnt      = (int*)(ws + OFF_CNT);
  int*   segm     = (int*)(ws + OFF_SEGM);
  int*   listTok  = (int*)(ws + OFF_LTOK);
  float* smapG    = (float*)(ws + OFF_SMAPG);
  u16*   hws      = (u16*)(ws + OFF_HWS);
  u16*   eoTok    = (u16*)(ws + OFF_EOTOK);
  u16*   w1t      = (u16*)(ws + OFF_W1T);
  u16*   w2t      = (u16*)(ws + OFF_W2T);
  float* b1p      = (float*)(ws + OFF_B1P);
  float* Wpr      = (float*)(ws + OFF_WPR);
  float* br1p     = (float*)(ws + OFF_BR1P);

  float* outN = (float*)d_out;
  float* outG = outN + (size_t)NTOK * 128;
  float* outP = outG + (size_t)NTOK * 8;

  hipMemsetAsync(ws + OFF_CNT, 0, 256, stream);
  k0_pre<<<659, 256, 0, stream>>>(Wp, bp, Wr1, br1, Wf, bfv, We1h, We1f, be1, We2,
                                  Wpr, br1p, w1t, w2t, b1p);
  k1_router<<<1024, 256, 0, stream>>>(hidden, feat, ln_g, ln_b, Wr1, Wr2, br2, seqlen,
                                      sidx, Wpr, br1p, outG, outP, hws, cnt,
                                      listTok, smapG);
  k1b_prefix<<<1, 64, 0, stream>>>(cnt, segm);
  k2_experts<<<2056, 256, 0, stream>>>(feat, hws, w1t, w2t, b1p, be2, eidx,
                                       cnt, segm, listTok, eoTok);
  k3_combine<<<1024, 256, 0, stream>>>(hidden, smapG, eoTok, alpha, outN);
}